// Round 3
// baseline (117.727 us; speedup 1.0000x reference)
//
#include <hip/hip_runtime.h>
#include <math.h>

typedef float2 cplx;
__device__ __forceinline__ cplx mk(float r, float i){ return make_float2(r, i); }

#define NT 256

// One fused conv iteration on a 16-amp half-group held in registers.
// Index space: state index l; window occupies bits LO..LO+4:
//   bit LO+4 = wire i, LO+3 = wire i+1, LO+2 = wire i+2 (untouched; split bit c),
//   bit LO+1 = wire i+3, LO = wire i+4.
// Register index m (4 bits): [3]=wire i, [2]=wire i+1, [1]=wire i+3, [0]=wire i+4.
// SH/MASK define the LDS anti-conflict swizzle phys = l ^ ((l>>SH)&MASK).
template<int LO, int SH, int MASK>
__device__ __forceinline__ void do_iter(cplx* S, int g, int c,
    float hc0, float hs0, float hc1, float hs1, float hc2, float hs2,
    float hcx, float hsx, float hc4, float hs4)
{
  const int base = ((g >> LO) << (LO + 5)) | (g & ((1 << LO) - 1)) | (c << (LO + 2));
  cplx A[16];
  int la[16];
  #pragma unroll
  for (int m = 0; m < 16; ++m){
    int off = (((m >> 3) & 1) << (LO + 4)) | (((m >> 2) & 1) << (LO + 3))
            | (((m >> 1) & 1) << (LO + 1)) | ((m & 1) << LO);
    int l = base | off;
    la[m] = l ^ ((l >> SH) & MASK);
    A[m] = S[la[m]];
  }
  // G1: RY0 on wire i (bit 3)
  #pragma unroll
  for (int p = 0; p < 8; ++p){
    cplx a0 = A[p], a1 = A[p | 8];
    A[p]     = mk(hc0*a0.x - hs0*a1.x, hc0*a0.y - hs0*a1.y);
    A[p | 8] = mk(hs0*a0.x + hc0*a1.x, hs0*a0.y + hc0*a1.y);
  }
  // G2: CNOT(i -> i+3) then RY1 on i+3. ctl bit 3, tgt bit 1.
  #pragma unroll
  for (int q = 0; q < 16; ++q){
    if (q & 2) continue;
    cplx a0 = A[q], a1 = A[q | 2];
    if (q & 8){ // ctl=1: RY1*X = [[-s1,c1],[c1,s1]]
      A[q]     = mk(-hs1*a0.x + hc1*a1.x, -hs1*a0.y + hc1*a1.y);
      A[q | 2] = mk( hc1*a0.x + hs1*a1.x,  hc1*a0.y + hs1*a1.y);
    } else {
      A[q]     = mk( hc1*a0.x - hs1*a1.x,  hc1*a0.y - hs1*a1.y);
      A[q | 2] = mk( hs1*a0.x + hc1*a1.x,  hs1*a0.y + hc1*a1.y);
    }
  }
  // G3: RY2 on i+1 (bit 2); CNOT(i+1 -> i+4); RX0 on i+4 (bit 0)
  #pragma unroll
  for (int r = 0; r < 16; ++r){
    if (r & 5) continue;  // r in {0,2,8,10}
    cplx a00 = A[r], a01 = A[r | 1], a10 = A[r | 4], a11 = A[r | 5];
    cplx b00 = mk(hc2*a00.x - hs2*a10.x, hc2*a00.y - hs2*a10.y);
    cplx b01 = mk(hc2*a01.x - hs2*a11.x, hc2*a01.y - hs2*a11.y);
    cplx b10 = mk(hs2*a00.x + hc2*a10.x, hs2*a00.y + hc2*a10.y);
    cplx b11 = mk(hs2*a01.x + hc2*a11.x, hs2*a01.y + hc2*a11.y);
    cplx c10 = b11, c11 = b10;  // CNOT swap in ctl=1 half
    A[r]     = mk(hcx*b00.x + hsx*b01.y,  hcx*b00.y - hsx*b01.x);
    A[r | 1] = mk(hsx*b00.y + hcx*b01.x, -hsx*b00.x + hcx*b01.y);
    A[r | 4] = mk(hcx*c10.x + hsx*c11.y,  hcx*c10.y - hsx*c11.x);
    A[r | 5] = mk(hsx*c10.y + hcx*c11.x, -hsx*c10.x + hcx*c11.y);
  }
  // G4: CNOT(i+3 -> i+1) then RX1 on i+1. ctl bit 1, tgt bit 2.
  #pragma unroll
  for (int q = 0; q < 16; ++q){
    if (q & 4) continue;  // q in {0,1,2,3,8,9,10,11}
    cplx a0 = A[q], a1 = A[q | 4];
    if (q & 2){ // ctl=1: RX1*X = [[-i s,c],[c,-i s]]
      A[q]     = mk( hs4*a0.y + hc4*a1.x, -hs4*a0.x + hc4*a1.y);
      A[q | 4] = mk( hc4*a0.x + hs4*a1.y,  hc4*a0.y - hs4*a1.x);
    } else {    // RX1 = [[c,-i s],[-i s,c]]
      A[q]     = mk( hc4*a0.x + hs4*a1.y,  hc4*a0.y - hs4*a1.x);
      A[q | 4] = mk( hs4*a0.y + hc4*a1.x, -hs4*a0.x + hc4*a1.y);
    }
  }
  #pragma unroll
  for (int m = 0; m < 16; ++m) S[la[m]] = A[m];
}

__global__ __launch_bounds__(NT) void qsim_kernel(
    const float* __restrict__ x,     // (16,1,28,28)
    const float* __restrict__ kp,    // (2,5)
    float* __restrict__ pacc,        // (512,12) partials
    unsigned* __restrict__ cnt,      // memset to 0 before launch
    const float* __restrict__ w1, const float* __restrict__ b1,
    const float* __restrict__ w2, const float* __restrict__ b2,
    const float* __restrict__ w3, const float* __restrict__ b3,
    float* __restrict__ out)
{
  __shared__ cplx S[4096];      // 32 KB chunk (local idx bits 11..0 = wires 4..15)
  __shared__ cplx Psi[1024];    // 8 KB sub-state over wires 0..9 (bit 9-w)
  __shared__ float vc[16], vs[16], Pre[64], red[4 * 12];
  __shared__ int isLast;

  const int t = threadIdx.x;
  const int pair  = blockIdx.x & 31;
  const int chunk = blockIdx.x >> 5;   // global idx bits 15..12 = wires 0..3
  const int b = pair & 15;
  const int k = pair >> 4;

  // AvgPool2d(7,7) -> 16 angles
  if (t < 16){
    int i = t >> 2, j = t & 3;
    const float* xb = x + b*784 + (7*i)*28 + 7*j;
    float s = 0.f;
    #pragma unroll
    for (int u = 0; u < 7; ++u)
      #pragma unroll
      for (int v = 0; v < 7; ++v)
        s += xb[u*28 + v];
    float ang = s * (1.0f/49.0f) * 0.5f;
    vc[t] = cosf(ang);
    vs[t] = sinf(ang);
  }
  __syncthreads();

  // Psi0 product state over wires 0..9 (swizzled store)
  for (int h = t; h < 1024; h += NT){
    float p = 1.f;
    #pragma unroll
    for (int w = 0; w < 10; ++w)
      p *= ((h >> (9 - w)) & 1) ? vs[w] : vc[w];
    Psi[h ^ ((h >> 5) & 31)] = mk(p, 0.f);
  }
  if (t < 64){
    float p = 1.f;
    #pragma unroll
    for (int w = 10; w < 16; ++w)
      p *= ((t >> (15 - w)) & 1) ? vs[w] : vc[w];
    Pre[t] = p;
  }

  const float* p5 = kp + k*5;
  float hc0 = cosf(p5[0]*0.5f), hs0 = sinf(p5[0]*0.5f);
  float hc1 = cosf(p5[1]*0.5f), hs1 = sinf(p5[1]*0.5f);
  float hc2 = cosf(p5[2]*0.5f), hs2 = sinf(p5[2]*0.5f);
  float hcx = cosf(p5[3]*0.5f), hsx = sinf(p5[3]*0.5f);
  float hc4 = cosf(p5[4]*0.5f), hs4 = sinf(p5[4]*0.5f);
  __syncthreads();

  // Stage 1: iterations 0..5 on Psi. wire w -> bit 9-w; iter i: LO = 5-i.
  {
    int g = t & 31, c = (t >> 5) & 1;
    bool act = t < 64;
    if (act) do_iter<5,5,31>(Psi,g,c,hc0,hs0,hc1,hs1,hc2,hs2,hcx,hsx,hc4,hs4);
    __syncthreads();
    if (act) do_iter<4,5,31>(Psi,g,c,hc0,hs0,hc1,hs1,hc2,hs2,hcx,hsx,hc4,hs4);
    __syncthreads();
    if (act) do_iter<3,5,31>(Psi,g,c,hc0,hs0,hc1,hs1,hc2,hs2,hcx,hsx,hc4,hs4);
    __syncthreads();
    if (act) do_iter<2,5,31>(Psi,g,c,hc0,hs0,hc1,hs1,hc2,hs2,hcx,hsx,hc4,hs4);
    __syncthreads();
    if (act) do_iter<1,5,31>(Psi,g,c,hc0,hs0,hc1,hs1,hc2,hs2,hcx,hsx,hc4,hs4);
    __syncthreads();
    if (act) do_iter<0,5,31>(Psi,g,c,hc0,hs0,hc1,hs1,hc2,hs2,hcx,hsx,hc4,hs4);
    __syncthreads();
  }

  // Expand: S[l] = Psi[(chunk<<6)|(l>>6)] * Pre[l&63]
  for (int l = t; l < 4096; l += NT){
    int h = (chunk << 6) | (l >> 6);
    cplx ph = Psi[h ^ ((h >> 5) & 31)];
    float pr = Pre[l & 63];
    S[l ^ ((l >> 6) & 63)] = mk(ph.x * pr, ph.y * pr);
  }
  __syncthreads();

  // Stage 3: iterations 6..11 on chunk. wire w -> local bit 15-w; iter i: LO = 11-i.
  {
    int g = t & 127, c = (t >> 7) & 1;
    do_iter<5,6,63>(S,g,c,hc0,hs0,hc1,hs1,hc2,hs2,hcx,hsx,hc4,hs4);
    __syncthreads();
    do_iter<4,6,63>(S,g,c,hc0,hs0,hc1,hs1,hc2,hs2,hcx,hsx,hc4,hs4);
    __syncthreads();
    do_iter<3,6,63>(S,g,c,hc0,hs0,hc1,hs1,hc2,hs2,hcx,hsx,hc4,hs4);
    __syncthreads();
    do_iter<2,6,63>(S,g,c,hc0,hs0,hc1,hs1,hc2,hs2,hcx,hsx,hc4,hs4);
    __syncthreads();
    do_iter<1,6,63>(S,g,c,hc0,hs0,hc1,hs1,hc2,hs2,hcx,hsx,hc4,hs4);
    __syncthreads();
    do_iter<0,6,63>(S,g,c,hc0,hs0,hc1,hs1,hc2,hs2,hcx,hsx,hc4,hs4);
    __syncthreads();
  }

  // Measurement: final CNOT block folded into parity masks (wires {w,w+1,w+3,w+4})
  float a12[12];
  #pragma unroll
  for (int w = 0; w < 12; ++w) a12[w] = 0.f;
  for (int l = t; l < 4096; l += NT){
    cplx v = S[l ^ ((l >> 6) & 63)];
    float p = v.x*v.x + v.y*v.y;
    int idx = (chunk << 12) | l;
    #pragma unroll
    for (int w = 0; w < 12; ++w)
      a12[w] += (__popc(idx & (27u << (11 - w))) & 1) ? -p : p;
  }
  #pragma unroll
  for (int off = 32; off > 0; off >>= 1)
    #pragma unroll
    for (int w = 0; w < 12; ++w)
      a12[w] += __shfl_down(a12[w], off, 64);
  int lane = t & 63, wv = t >> 6;
  if (lane == 0){
    #pragma unroll
    for (int w = 0; w < 12; ++w) red[wv*12 + w] = a12[w];
  }
  __syncthreads();
  if (t < 12){
    float s = red[t] + red[12 + t] + red[24 + t] + red[36 + t];
    __hip_atomic_store(&pacc[blockIdx.x*12 + t], s, __ATOMIC_RELAXED, __HIP_MEMORY_SCOPE_AGENT);
  }
  __syncthreads();

  // Elect last-arriving block to run the MLP
  if (t == 0){
    __threadfence();
    unsigned old = __hip_atomic_fetch_add(cnt, 1u, __ATOMIC_ACQ_REL, __HIP_MEMORY_SCOPE_AGENT);
    isLast = (old == 511u);
  }
  __syncthreads();
  if (!isLast) return;

  // ---- winner block: reduce partials + MLP ----
  float* mf    = (float*)S;   // reuse LDS
  float* feats = mf;          // 16*24
  float* h1    = mf + 384;    // 16*128
  float* h2    = mf + 2432;   // 16*64

  for (int e = t; e < 384; e += NT){
    int w = e % 12, p = e / 12;          // p = k*16+b
    int bb = p & 15, kk = p >> 4;
    float s = 0.f;
    #pragma unroll
    for (int cc = 0; cc < 16; ++cc)
      s += __hip_atomic_load(&pacc[(cc*32 + p)*12 + w], __ATOMIC_RELAXED, __HIP_MEMORY_SCOPE_AGENT);
    feats[bb*24 + kk*12 + w] = s;
  }
  __syncthreads();
  for (int e = t; e < 2048; e += NT){
    int bb = e >> 7, j = e & 127;
    float s = b1[j];
    #pragma unroll 8
    for (int q = 0; q < 24; ++q) s = fmaf(feats[bb*24 + q], w1[j*24 + q], s);
    h1[e] = fmaxf(s, 0.f);
  }
  __syncthreads();
  for (int e = t; e < 1024; e += NT){
    int bb = e >> 6, j = e & 63;
    float s = b2[j];
    #pragma unroll 8
    for (int q = 0; q < 128; ++q) s = fmaf(h1[bb*128 + q], w2[j*128 + q], s);
    h2[e] = fmaxf(s, 0.f);
  }
  __syncthreads();
  if (t < 64){
    int bb = t >> 2, j = t & 3;
    float s = b3[j];
    #pragma unroll 8
    for (int q = 0; q < 64; ++q) s = fmaf(h2[bb*64 + q], w3[j*64 + q], s);
    out[t] = s;
  }
}

extern "C" void kernel_launch(void* const* d_in, const int* in_sizes, int n_in,
                              void* d_out, int out_size, void* d_ws, size_t ws_size,
                              hipStream_t stream) {
  const float* x  = (const float*)d_in[0];
  const float* kp = (const float*)d_in[1];
  const float* w1 = (const float*)d_in[2];
  const float* b1 = (const float*)d_in[3];
  const float* w2 = (const float*)d_in[4];
  const float* b2 = (const float*)d_in[5];
  const float* w3 = (const float*)d_in[6];
  const float* b3 = (const float*)d_in[7];
  float* out = (float*)d_out;
  float* pacc = (float*)d_ws;                         // 512*12 floats
  unsigned* cnt = (unsigned*)((char*)d_ws + 6144*4);  // arrival counter

  hipMemsetAsync(cnt, 0, sizeof(unsigned), stream);
  qsim_kernel<<<512, NT, 0, stream>>>(x, kp, pacc, cnt, w1, b1, w2, b2, w3, b3, out);
}